// Round 7
// baseline (340.356 us; speedup 1.0000x reference)
//
#include <hip/hip_runtime.h>

// ---------------------------------------------------------------------------
// Factorized algorithm (verified rounds 2-11). Shells = ascending r2 rank:
//   r2 in {0,1,2,3,4,5,6,8,9,12} -> shell 0..9
// y[l][r][d][z] = sum_{taps t in shell r} sph_l[t] * x[d, xo+i, yo+j, z+kk]
// conv_r[s,e,z] = sum_{r,d} wfull[wig_w[s], r, e, d] * y[wig_b[s]][r][d][z]
// s=0:(w,b)=(0,0); s=1..9: w=1+(s-1)/3, b=1+(s-1)%3
// Round 17 (base, 153us): 4 super-phases x 4 d, 4 z/thread stage-1, packed
//   symmetric CT in LDS, Y2 k-parity XOR banking, XT pitch-20.
// Round 18 (reverted): CT->global hoisted 100 loop-invariant loads into
//   VGPRs (128->192) -> 2 blocks/CU -> 324us. CT stays in LDS.
// Round 19: stage-2 E=4/Z=1. Decode (e4,yo4,z12): per k ONE ds_read_b128
//   (l0..3 at single z) + 4 W dwordx4 from global (VMEM pipe, idle).
//   Stage-2 LDS instrs halve (80->40/phase). Y2 read is <=2-way by
//   pigeonhole (16 lines / 8 groups) but 4 e-lanes broadcast per line so
//   the instr is data-light. Output: 4 scalar dword stores (write-amp
//   harmless at 1.4% HBM). acc [10][4] = 40 regs unchanged.
//   NO launch_bounds min-waves (r14), stages in separate intervals (r16).
// ---------------------------------------------------------------------------

// prep: W2[p8][k20][e16][w4] (k=2r+di, d=2p+di) + CT3[l][25][4] packed
__global__ void prep_kernel(const float* __restrict__ weight,     // (4,9,16,16)
                            const float* __restrict__ zw,         // (16,16)
                            const float* __restrict__ bf,         // (4,10,125)
                            float* __restrict__ W2,               // 10240 f32
                            float* __restrict__ TAB)              // 400 f32
{
    int t = blockIdx.x * 256 + threadIdx.x;
    if (t < 10240) {
        int w = t & 3;
        int e = (t >> 2) & 15;
        int k = (t >> 6) % 20;
        int p = t / 1280;
        int r = k >> 1, di = k & 1, d = 2 * p + di;
        float v;
        if (r == 0) v = (w == 0) ? zw[e * 16 + d] : 0.f;
        else        v = weight[((w * 9 + (r - 1)) * 16 + e) * 16 + d];
        W2[t] = v;
    } else if (t < 10240 + 400) {
        int q = t - 10240;           // [l4][25][4] = {c(kk=0),c(1),c(2),sign}
        int l = q / 100;
        int rem = q % 100;
        int slice = rem / 4, qq = rem & 3;
        float s;
        if (qq == 3) {
            s = (l == 2) ? -1.f : 1.f;   // c(3)=s*c(1), c(4)=s*c(0)
        } else {
            s = 0.f;
            int tap = slice * 5 + qq;
            for (int r = 0; r < 10; ++r) s += bf[(l * 10 + r) * 125 + tap];
        }
        TAB[q] = s;                  // sph_l[tap] (masks partition the cube)
    }
}

__global__ __launch_bounds__(192) void fused_kernel(
    const float* __restrict__ x,    // (2,16,40,40,40)
    const float* __restrict__ W2,   // [p][k20][e16][w4]
    const float* __restrict__ TAB,  // CT3 [l][25][4]
    const float* __restrict__ g,    // (27,10)
    const float* __restrict__ w_i,  // (3,)
    const float* __restrict__ bias, // (16,)
    float* __restrict__ out)        // (2,16,36,36,36)
{
    __shared__ float Y2[7680];      // [k40][bank-permuted (yo,z,l)] see below
    __shared__ float CT[400];       // [l4][25][4] packed symmetric coeffs
    __shared__ float XT[3232];      // [sd4 pitch 808][i5][row8][20]

    const int tid = threadIdx.x;

    // XCD-chunked swizzle: 1944 blocks = 8 XCDs x 243 contiguous wgids
    const int bid  = blockIdx.x;
    const int wgid = (bid & 7) * 243 + (bid >> 3);
    const int xo  = wgid % 36;
    const int yoq = (wgid / 36) % 9;
    const int zs  = (wgid / 324) % 3;   // z base = 12*zs
    const int bb  = wgid / 972;

    // stage-1 decode: zt = wave (3), lane -> (sd4, l4, yo4); 4 z per thread
    const int s_zt = tid >> 6;          // 0..2, z = 4*s_zt + zz
    const int lane = tid & 63;
    const int s_sd = lane >> 4;         // 0..3  (d = 4*pp + s_sd)
    const int s_l  = (lane >> 2) & 3;
    const int s_yo = lane & 3;
    // stage-2 decode (e4, yo4, z12): e = 4*c_e + ee, single z
    const int c_e  = tid & 3;
    const int c_yo = (tid >> 2) & 3;
    const int c_z  = tid >> 4;          // 0..11

    for (int idx = tid; idx < 400; idx += 192) CT[idx] = TAB[idx];

    constexpr int RANKT[13] = {0, 1, 2, 3, 4, 5, 6, 0, 7, 8, 0, 0, 9};

    float acc[10][4];   // [s][ee] = 40 regs
    #pragma unroll
    for (int s = 0; s < 10; ++s)
        #pragma unroll
        for (int ee = 0; ee < 4; ++ee) acc[s][ee] = 0.f;

    // Y2 word(k', yo, z, l) = k'*192 + (z&1)*96 + (z>>2)*32
    //                         + (((z>>1)&1) ^ (k'&1))*16 + yo*4 + l
    // stage-1 writes: 2-way (free); stage-2 reads <=2-way data-light.
    const int s1b  = s_sd & 1;
    const int kb   = (s_sd >> 1) * 20 + s1b;     // k' = kb + 2r
    const int wb0  = s_zt * 32 + s_yo * 4 + s_l;
    const int offa = s1b ? 16 : 0;               // zz=0,1 slot
    const int offb = 16 - offa;                  // zz=2,3 slot
    const int ybA  = (c_z & 1) * 96 + (c_z >> 2) * 32
                   + (((c_z >> 1) & 1)) * 16 + c_yo * 4;          // k' even
    const int ybB  = ybA ^ 16;                                     // k' odd

    // ---- XT staging geometry: 640 float4 per super-phase, 4 slots ----
    // decode j in LOW 3 bits -> conflict-free b128 LDS writes
    int xtoff[4], goff[4];
    #pragma unroll
    for (int q = 0; q < 4; ++q) {
        const int idx = tid + 192 * q;
        const int j  = idx & 7;
        const int zq = (idx >> 3) & 3;
        const int ii = (idx >> 5) % 5;
        const int sd = idx / 160;               // 0..3 (idx<640)
        xtoff[q] = sd * 808 + (ii * 8 + j) * 20 + 4 * zq;
        goff[q]  = sd * 64000 + ((xo + ii) * 40 + yoq * 4 + j) * 40
                   + zs * 12 + 4 * zq;
    }
    const bool has3 = tid < 64;                 // slot 3 active iff idx<640
    const float* xbase = x + bb * 1024000;

    // prologue: XT(0) direct; prefetch super-phase 1
    {
        float4 v0 = *(const float4*)(xbase + goff[0]);
        float4 v1 = *(const float4*)(xbase + goff[1]);
        float4 v2 = *(const float4*)(xbase + goff[2]);
        float4 v3 = has3 ? *(const float4*)(xbase + goff[3])
                         : make_float4(0.f, 0.f, 0.f, 0.f);
        *(float4*)(XT + xtoff[0]) = v0;
        *(float4*)(XT + xtoff[1]) = v1;
        *(float4*)(XT + xtoff[2]) = v2;
        if (has3) *(float4*)(XT + xtoff[3]) = v3;
    }
    float4 pre[4];
    {
        const float* b1 = xbase + 256000;
        pre[0] = *(const float4*)(b1 + goff[0]);
        pre[1] = *(const float4*)(b1 + goff[1]);
        pre[2] = *(const float4*)(b1 + goff[2]);
        pre[3] = has3 ? *(const float4*)(b1 + goff[3])
                      : make_float4(0.f, 0.f, 0.f, 0.f);
    }

    for (int pp = 0; pp < 4; ++pp) {
        __syncthreads();   // A: XT(pp) ready; stage-2(pp-1) done (Y2 free)
        // ---- stage 1: 4 z, d = 4*pp + s_sd, l = s_l (from XT + CT) ----
        {
            float yreg[10][4];
            #pragma unroll
            for (int r = 0; r < 10; ++r) {
                yreg[r][0] = 0.f; yreg[r][1] = 0.f;
                yreg[r][2] = 0.f; yreg[r][3] = 0.f;
            }
            const float* xt  = XT + s_sd * 808 + 4 * s_zt;
            const float* ctp = CT + s_l * 100;
            #pragma unroll
            for (int i = 0; i < 5; ++i) {
                #pragma unroll
                for (int j = 0; j < 5; ++j) {
                    const float* rp = xt + (i * 8 + s_yo + j) * 20;
                    const float4 xa = *(const float4*)rp;
                    const float4 xb = *(const float4*)(rp + 4);
                    const float xv[8] = {xa.x, xa.y, xa.z, xa.w,
                                         xb.x, xb.y, xb.z, xb.w};
                    const float4 cc = *(const float4*)(ctp + (i * 5 + j) * 4);
                    const int dij = (i - 2) * (i - 2) + (j - 2) * (j - 2);
                    const int r04 = RANKT[dij + 4];
                    const int r13 = RANKT[dij + 1];
                    const int r2c = RANKT[dij];
                    #pragma unroll
                    for (int zz = 0; zz < 4; ++zz) {
                        const float t04 = fmaf(cc.w, xv[zz + 4], xv[zz]);
                        const float t13 = fmaf(cc.w, xv[zz + 3], xv[zz + 1]);
                        yreg[r04][zz] = fmaf(cc.x, t04, yreg[r04][zz]);
                        yreg[r13][zz] = fmaf(cc.y, t13, yreg[r13][zz]);
                        yreg[r2c][zz] = fmaf(cc.z, xv[zz + 2], yreg[r2c][zz]);
                    }
                }
            }
            #pragma unroll
            for (int r = 0; r < 10; ++r) {
                const int w0 = (kb + 2 * r) * 192 + wb0;
                Y2[w0 + offa]      = yreg[r][0];   // pairs fuse to ds_write2
                Y2[w0 + offa + 96] = yreg[r][1];
                Y2[w0 + offb]      = yreg[r][2];
                Y2[w0 + offb + 96] = yreg[r][3];
            }
        }
        __syncthreads();   // B: Y2 ready; XT(pp) readers done
        // ---- write XT(pp+1) from prefetch; issue loads for pp+2 ----
        if (pp < 3) {
            *(float4*)(XT + xtoff[0]) = pre[0];
            *(float4*)(XT + xtoff[1]) = pre[1];
            *(float4*)(XT + xtoff[2]) = pre[2];
            if (has3) *(float4*)(XT + xtoff[3]) = pre[3];
            if (pp < 2) {
                const float* bn = xbase + (pp + 2) * 256000;
                pre[0] = *(const float4*)(bn + goff[0]);
                pre[1] = *(const float4*)(bn + goff[1]);
                pre[2] = *(const float4*)(bn + goff[2]);
                if (has3) pre[3] = *(const float4*)(bn + goff[3]);
            }
        }
        // ---- stage 2 (E=4, Z=1): per k ONE Y2 b128 + 4 W dwordx4 ----
        {
            const float* W2p = W2 + pp * 2560 + c_e * 16;
            #pragma unroll
            for (int k = 0; k < 40; ++k) {
                const float4 wv0 = *(const float4*)(W2p + k * 64);
                const float4 wv1 = *(const float4*)(W2p + k * 64 + 4);
                const float4 wv2 = *(const float4*)(W2p + k * 64 + 8);
                const float4 wv3 = *(const float4*)(W2p + k * 64 + 12);
                const float4 yv = *(const float4*)(Y2 + k * 192
                                                   + ((k & 1) ? ybB : ybA));
                {   // b = 0 pairs only with w = 0 -> s = 0
                    acc[0][0] = fmaf(wv0.x, yv.x, acc[0][0]);
                    acc[0][1] = fmaf(wv1.x, yv.x, acc[0][1]);
                    acc[0][2] = fmaf(wv2.x, yv.x, acc[0][2]);
                    acc[0][3] = fmaf(wv3.x, yv.x, acc[0][3]);
                }
                #pragma unroll
                for (int b = 1; b < 4; ++b) {
                    const float yb_ = (b == 1) ? yv.y : (b == 2) ? yv.z : yv.w;
                    #pragma unroll
                    for (int w = 1; w < 4; ++w) {
                        const int s = 1 + (w - 1) * 3 + (b - 1);
                        const float a0 = (w == 1) ? wv0.y : ((w == 2) ? wv0.z : wv0.w);
                        const float a1 = (w == 1) ? wv1.y : ((w == 2) ? wv1.z : wv1.w);
                        const float a2 = (w == 1) ? wv2.y : ((w == 2) ? wv2.z : wv2.w);
                        const float a3 = (w == 1) ? wv3.y : ((w == 2) ? wv3.z : wv3.w);
                        acc[s][0] = fmaf(a0, yb_, acc[s][0]);
                        acc[s][1] = fmaf(a1, yb_, acc[s][1]);
                        acc[s][2] = fmaf(a2, yb_, acc[s][2]);
                        acc[s][3] = fmaf(a3, yb_, acc[s][3]);
                    }
                }
            }
        }
    }

    // ---- epilogue: SO(3)-grid + self-normalized pooling (4 e x 1 z) ----
    const float wi0 = w_i[0], wi1 = w_i[1], wi2 = w_i[2];
    float num[4], den[4];
    #pragma unroll
    for (int ee = 0; ee < 4; ++ee) { num[ee] = 0.f; den[ee] = 0.f; }
    #pragma unroll
    for (int q = 0; q < 27; ++q) {
        const float wl = ((q / 3) % 3 == 0) ? wi0 : (((q / 3) % 3 == 1) ? wi1 : wi2);
        float gv[10];
        #pragma unroll
        for (int s = 0; s < 10; ++s) gv[s] = g[q * 10 + s];  // uniform -> s_load
        #pragma unroll
        for (int ee = 0; ee < 4; ++ee) {
            float v = 0.f;
            #pragma unroll
            for (int s = 0; s < 10; ++s) v = fmaf(acc[s][ee], gv[s], v);
            v = fmaxf(v, 0.f);
            den[ee] = fmaf(v, wl, den[ee]);
            num[ee] = fmaf(v * v, wl, num[ee]);
        }
    }
    #pragma unroll
    for (int ee = 0; ee < 4; ++ee) {
        const int e = 4 * c_e + ee;
        const float bz = bias[e];
        float* op = out + (((bb * 16 + e) * 36 + xo) * 36 + (yoq * 4 + c_yo)) * 36
                        + zs * 12 + c_z;
        *op = num[ee] / (den[ee] + 1e-16f) + bz;
    }
}

extern "C" void kernel_launch(void* const* d_in, const int* in_sizes, int n_in,
                              void* d_out, int out_size, void* d_ws, size_t ws_size,
                              hipStream_t stream) {
    const float* x          = (const float*)d_in[0];
    const float* weight     = (const float*)d_in[1];
    const float* zeroweight = (const float*)d_in[2];
    const float* bias       = (const float*)d_in[3];
    const float* g          = (const float*)d_in[4];
    const float* w_i        = (const float*)d_in[5];
    const float* bf         = (const float*)d_in[6];
    float* outp = (float*)d_out;

    float* W2  = (float*)d_ws;            // 10240 f32
    float* TAB = (float*)d_ws + 10240;    // 400 f32 (packed CT3 layout)

    prep_kernel<<<42, 256, 0, stream>>>(weight, zeroweight, bf, W2, TAB);
    // 1944 blocks = 36 xo * 9 yoq * 3 zs * 2 b, XCD-swizzled in-kernel
    fused_kernel<<<1944, 192, 0, stream>>>(x, W2, TAB, g, w_i, bias, outp);
}

// Round 8
// 332.136 us; speedup vs baseline: 1.0248x; 1.0248x over previous
//
#include <hip/hip_runtime.h>

// ---------------------------------------------------------------------------
// Factorized algorithm (verified rounds 2-11). Shells = ascending r2 rank:
//   r2 in {0,1,2,3,4,5,6,8,9,12} -> shell 0..9
// y[l][r][d][z] = sum_{taps t in shell r} sph_l[t] * x[d, xo+i, yo+j, z+kk]
// conv_r[s,e,z] = sum_{r,d} wfull[wig_w[s], r, e, d] * y[wig_b[s]][r][d][z]
// s=0:(w,b)=(0,0); s=1..9: w=1+(s-1)/3, b=1+(s-1)%3
// Round 17 (153us): 4 super-phases x 4 d, 4z/thread stage-1, packed CT,
//   Y2 k-parity XOR banking. Round 18/19 regressions reverted (CT stays in
//   LDS; stage-2 stays E=2/Z=2 with 2 W-loads + 2 Y-b128 per k).
// Round 20: occupancy attack. Each super-phase splits into 2 half-phases
//   over sd-pairs: stage-1 does 2 d (20 k-rows) per interval -> Y2 HALVES
//   to 3840 floats. LDS = 15360 + 12928 + 1600 = 29888B -> 5 blocks/CU
//   (15 waves vs 9). Stage-1 2z/thread, x-reads = 3 float2 at per-lane z0
//   (compile-time indices, no runtime-indexed arrays). Stage-2 = r13's
//   verified 20-k loop, W2 slice p = 2pp+h (d = 2p+(k&1) matches layout).
//   Cost: x/CT LDS instrs ~1.7x, barriers 16 - occupancy must beat it.
//   NO launch_bounds min-waves (r14), stages in separate intervals (r16).
// ---------------------------------------------------------------------------

// prep: W2[p8][k20][e16][w4] (k=2r+di, d=2p+di) + CT3[l][25][4] packed
__global__ void prep_kernel(const float* __restrict__ weight,     // (4,9,16,16)
                            const float* __restrict__ zw,         // (16,16)
                            const float* __restrict__ bf,         // (4,10,125)
                            float* __restrict__ W2,               // 10240 f32
                            float* __restrict__ TAB)              // 400 f32
{
    int t = blockIdx.x * 256 + threadIdx.x;
    if (t < 10240) {
        int w = t & 3;
        int e = (t >> 2) & 15;
        int k = (t >> 6) % 20;
        int p = t / 1280;
        int r = k >> 1, di = k & 1, d = 2 * p + di;
        float v;
        if (r == 0) v = (w == 0) ? zw[e * 16 + d] : 0.f;
        else        v = weight[((w * 9 + (r - 1)) * 16 + e) * 16 + d];
        W2[t] = v;
    } else if (t < 10240 + 400) {
        int q = t - 10240;           // [l4][25][4] = {c(kk=0),c(1),c(2),sign}
        int l = q / 100;
        int rem = q % 100;
        int slice = rem / 4, qq = rem & 3;
        float s;
        if (qq == 3) {
            s = (l == 2) ? -1.f : 1.f;   // c(3)=s*c(1), c(4)=s*c(0)
        } else {
            s = 0.f;
            int tap = slice * 5 + qq;
            for (int r = 0; r < 10; ++r) s += bf[(l * 10 + r) * 125 + tap];
        }
        TAB[q] = s;                  // sph_l[tap] (masks partition the cube)
    }
}

__global__ __launch_bounds__(192) void fused_kernel(
    const float* __restrict__ x,    // (2,16,40,40,40)
    const float* __restrict__ W2,   // [p][k20][e16][w4]
    const float* __restrict__ TAB,  // CT3 [l][25][4]
    const float* __restrict__ g,    // (27,10)
    const float* __restrict__ w_i,  // (3,)
    const float* __restrict__ bias, // (16,)
    float* __restrict__ out)        // (2,16,36,36,36)
{
    __shared__ float Y2[3840];      // [k20][bank-permuted (yo,z,l)]
    __shared__ float CT[400];       // [l4][25][4] packed symmetric coeffs
    __shared__ float XT[3232];      // [sd4 pitch 808][i5][row8][20]

    const int tid = threadIdx.x;

    // XCD-chunked swizzle: 1944 blocks = 8 XCDs x 243 contiguous wgids
    const int bid  = blockIdx.x;
    const int wgid = (bid & 7) * 243 + (bid >> 3);
    const int xo  = wgid % 36;
    const int yoq = (wgid / 36) % 9;
    const int zs  = (wgid / 324) % 3;   // z base = 12*zs
    const int bb  = wgid / 972;

    // stage-1 decode: zt6 (z = 2*zt + zz), sdl2, l4, yo4 ; 2 z per thread
    const int s_zt = tid >> 5;          // 0..5
    const int sdl  = (tid >> 4) & 1;    // d parity within half-phase
    const int s_l  = (tid >> 2) & 3;
    const int s_yo = tid & 3;
    // stage-2 decode (e8, yo4, zt6): e = 2*c_e+{0,1}, z = 2*c_zt+{0,1}
    const int c_e  = tid & 7;
    const int c_yo = (tid >> 3) & 3;
    const int c_zt = tid / 32;

    for (int idx = tid; idx < 400; idx += 192) CT[idx] = TAB[idx];

    constexpr int RANKT[13] = {0, 1, 2, 3, 4, 5, 6, 0, 7, 8, 0, 0, 9};

    float acc[10][2][2];   // [s][e-sub][z] = 40 regs
    #pragma unroll
    for (int s = 0; s < 10; ++s)
        #pragma unroll
        for (int ee = 0; ee < 2; ++ee) { acc[s][ee][0] = 0.f; acc[s][ee][1] = 0.f; }

    // Y2 word(k', yo, z, l) = k'*192 + (z&1)*96 + (z>>2)*32
    //                         + (((z>>1)&1) ^ (k'&1))*16 + yo*4 + l
    // k' = 2r + sdl (20 rows). stage-1 writes ds_write2 pairs (z, z+1);
    // stage-2 reads conflict-free (r17 banking, k-parity XOR).
    const int wb0 = (s_zt >> 1) * 32 + ((s_zt & 1) ^ sdl) * 16
                  + s_yo * 4 + s_l;
    const int ybA = (c_zt >> 1) * 32 + (c_zt & 1) * 16 + c_yo * 4;  // k' even
    const int ybB = ybA ^ 16;                                        // k' odd

    // ---- XT staging geometry: 640 float4 per super-phase, 4 slots ----
    // decode j in LOW 3 bits -> conflict-free b128 LDS writes
    int xtoff[4], goff[4];
    #pragma unroll
    for (int q = 0; q < 4; ++q) {
        const int idx = tid + 192 * q;
        const int j  = idx & 7;
        const int zq = (idx >> 3) & 3;
        const int ii = (idx >> 5) % 5;
        const int sd = idx / 160;               // 0..3 (idx<640)
        xtoff[q] = sd * 808 + (ii * 8 + j) * 20 + 4 * zq;
        goff[q]  = sd * 64000 + ((xo + ii) * 40 + yoq * 4 + j) * 40
                   + zs * 12 + 4 * zq;
    }
    const bool has3 = tid < 64;                 // slot 3 active iff idx<640
    const float* xbase = x + bb * 1024000;

    // prologue: XT(0) direct; prefetch super-phase 1
    {
        float4 v0 = *(const float4*)(xbase + goff[0]);
        float4 v1 = *(const float4*)(xbase + goff[1]);
        float4 v2 = *(const float4*)(xbase + goff[2]);
        float4 v3 = has3 ? *(const float4*)(xbase + goff[3])
                         : make_float4(0.f, 0.f, 0.f, 0.f);
        *(float4*)(XT + xtoff[0]) = v0;
        *(float4*)(XT + xtoff[1]) = v1;
        *(float4*)(XT + xtoff[2]) = v2;
        if (has3) *(float4*)(XT + xtoff[3]) = v3;
    }
    float4 pre[4];
    {
        const float* b1 = xbase + 256000;
        pre[0] = *(const float4*)(b1 + goff[0]);
        pre[1] = *(const float4*)(b1 + goff[1]);
        pre[2] = *(const float4*)(b1 + goff[2]);
        pre[3] = has3 ? *(const float4*)(b1 + goff[3])
                      : make_float4(0.f, 0.f, 0.f, 0.f);
    }

    for (int pp = 0; pp < 4; ++pp) {
        #pragma unroll
        for (int h = 0; h < 2; ++h) {
            __syncthreads();   // A: XT(pp) ready; prev stage-2 done (Y2 free)
            // ---- stage 1: 2 z, d = 4*pp + 2*h + sdl, l = s_l ----
            {
                const int s_sd = 2 * h + sdl;
                float yreg[10][2];
                #pragma unroll
                for (int r = 0; r < 10; ++r) { yreg[r][0] = 0.f; yreg[r][1] = 0.f; }
                // per-lane z0 folded into the address; indices compile-time
                const float* xt  = XT + s_sd * 808 + 2 * s_zt;
                const float* ctp = CT + s_l * 100;
                #pragma unroll
                for (int i = 0; i < 5; ++i) {
                    #pragma unroll
                    for (int j = 0; j < 5; ++j) {
                        const float* rp = xt + (i * 8 + s_yo + j) * 20;
                        const float2 A = *(const float2*)(rp);      // z0,z0+1
                        const float2 B = *(const float2*)(rp + 2);  // +2,+3
                        const float2 C = *(const float2*)(rp + 4);  // +4,+5
                        const float4 cc = *(const float4*)(ctp + (i * 5 + j) * 4);
                        const int dij = (i - 2) * (i - 2) + (j - 2) * (j - 2);
                        const int r04 = RANKT[dij + 4];
                        const int r13 = RANKT[dij + 1];
                        const int r2c = RANKT[dij];
                        // zz = 0
                        {
                            const float t04 = fmaf(cc.w, C.x, A.x);
                            const float t13 = fmaf(cc.w, B.y, A.y);
                            yreg[r04][0] = fmaf(cc.x, t04, yreg[r04][0]);
                            yreg[r13][0] = fmaf(cc.y, t13, yreg[r13][0]);
                            yreg[r2c][0] = fmaf(cc.z, B.x, yreg[r2c][0]);
                        }
                        // zz = 1
                        {
                            const float t04 = fmaf(cc.w, C.y, A.y);
                            const float t13 = fmaf(cc.w, C.x, B.x);
                            yreg[r04][1] = fmaf(cc.x, t04, yreg[r04][1]);
                            yreg[r13][1] = fmaf(cc.y, t13, yreg[r13][1]);
                            yreg[r2c][1] = fmaf(cc.z, B.y, yreg[r2c][1]);
                        }
                    }
                }
                #pragma unroll
                for (int r = 0; r < 10; ++r) {
                    const int w0 = (2 * r + sdl) * 192 + wb0;
                    Y2[w0]      = yreg[r][0];   // fuses into ds_write2_b32
                    Y2[w0 + 96] = yreg[r][1];
                }
            }
            __syncthreads();   // B: Y2 ready; stage-1 XT reads done
            // ---- after the 2nd half-phase, XT(pp) fully consumed ----
            if (h == 1 && pp < 3) {
                *(float4*)(XT + xtoff[0]) = pre[0];
                *(float4*)(XT + xtoff[1]) = pre[1];
                *(float4*)(XT + xtoff[2]) = pre[2];
                if (has3) *(float4*)(XT + xtoff[3]) = pre[3];
                if (pp < 2) {
                    const float* bn = xbase + (pp + 2) * 256000;
                    pre[0] = *(const float4*)(bn + goff[0]);
                    pre[1] = *(const float4*)(bn + goff[1]);
                    pre[2] = *(const float4*)(bn + goff[2]);
                    if (has3) pre[3] = *(const float4*)(bn + goff[3]);
                }
            }
            // ---- stage 2 (E=2,Z=2): 20 k, W2 slice p = 2*pp + h ----
            {
                const float* W2p = W2 + (2 * pp + h) * 1280 + c_e * 8;
                #pragma unroll
                for (int k = 0; k < 20; ++k) {
                    const float4 wv0 = *(const float4*)(W2p + k * 64);
                    const float4 wv1 = *(const float4*)(W2p + k * 64 + 4);
                    const float* yb = Y2 + k * 192 + ((k & 1) ? ybB : ybA);
                    const float4 yz0 = *(const float4*)(yb);       // l0..3 at z0
                    const float4 yz1 = *(const float4*)(yb + 96);  // l0..3 at z1
                    {   // b = 0 pairs only with w = 0 -> s = 0
                        acc[0][0][0] = fmaf(wv0.x, yz0.x, acc[0][0][0]);
                        acc[0][0][1] = fmaf(wv0.x, yz1.x, acc[0][0][1]);
                        acc[0][1][0] = fmaf(wv1.x, yz0.x, acc[0][1][0]);
                        acc[0][1][1] = fmaf(wv1.x, yz1.x, acc[0][1][1]);
                    }
                    #pragma unroll
                    for (int b = 1; b < 4; ++b) {
                        const float y0 = (b == 1) ? yz0.y : (b == 2) ? yz0.z : yz0.w;
                        const float y1 = (b == 1) ? yz1.y : (b == 2) ? yz1.z : yz1.w;
                        #pragma unroll
                        for (int w = 1; w < 4; ++w) {
                            const int s = 1 + (w - 1) * 3 + (b - 1);
                            const float w0 = (w == 1) ? wv0.y : ((w == 2) ? wv0.z : wv0.w);
                            const float w1 = (w == 1) ? wv1.y : ((w == 2) ? wv1.z : wv1.w);
                            acc[s][0][0] = fmaf(w0, y0, acc[s][0][0]);
                            acc[s][0][1] = fmaf(w0, y1, acc[s][0][1]);
                            acc[s][1][0] = fmaf(w1, y0, acc[s][1][0]);
                            acc[s][1][1] = fmaf(w1, y1, acc[s][1][1]);
                        }
                    }
                }
            }
        }
    }

    // ---- epilogue: SO(3)-grid + self-normalized pooling (2 e x 2 z) ----
    const float wi0 = w_i[0], wi1 = w_i[1], wi2 = w_i[2];
    float num[2][2], den[2][2];
    #pragma unroll
    for (int ee = 0; ee < 2; ++ee) { num[ee][0] = num[ee][1] = 0.f; den[ee][0] = den[ee][1] = 0.f; }
    #pragma unroll
    for (int q = 0; q < 27; ++q) {
        const float wl = ((q / 3) % 3 == 0) ? wi0 : (((q / 3) % 3 == 1) ? wi1 : wi2);
        float gv[10];
        #pragma unroll
        for (int s = 0; s < 10; ++s) gv[s] = g[q * 10 + s];  // uniform -> s_load
        #pragma unroll
        for (int ee = 0; ee < 2; ++ee) {
            #pragma unroll
            for (int zi = 0; zi < 2; ++zi) {
                float v = 0.f;
                #pragma unroll
                for (int s = 0; s < 10; ++s) v = fmaf(acc[s][ee][zi], gv[s], v);
                v = fmaxf(v, 0.f);
                den[ee][zi] = fmaf(v, wl, den[ee][zi]);
                num[ee][zi] = fmaf(v * v, wl, num[ee][zi]);
            }
        }
    }
    #pragma unroll
    for (int ee = 0; ee < 2; ++ee) {
        const int e = 2 * c_e + ee;
        const float bz = bias[e];
        float* op = out + (((bb * 16 + e) * 36 + xo) * 36 + (yoq * 4 + c_yo)) * 36
                        + zs * 12 + 2 * c_zt;
        *(float2*)op = make_float2(num[ee][0] / (den[ee][0] + 1e-16f) + bz,
                                   num[ee][1] / (den[ee][1] + 1e-16f) + bz);
    }
}

extern "C" void kernel_launch(void* const* d_in, const int* in_sizes, int n_in,
                              void* d_out, int out_size, void* d_ws, size_t ws_size,
                              hipStream_t stream) {
    const float* x          = (const float*)d_in[0];
    const float* weight     = (const float*)d_in[1];
    const float* zeroweight = (const float*)d_in[2];
    const float* bias       = (const float*)d_in[3];
    const float* g          = (const float*)d_in[4];
    const float* w_i        = (const float*)d_in[5];
    const float* bf         = (const float*)d_in[6];
    float* outp = (float*)d_out;

    float* W2  = (float*)d_ws;            // 10240 f32
    float* TAB = (float*)d_ws + 10240;    // 400 f32 (packed CT3 layout)

    prep_kernel<<<42, 256, 0, stream>>>(weight, zeroweight, bf, W2, TAB);
    // 1944 blocks = 36 xo * 9 yoq * 3 zs * 2 b, XCD-swizzled in-kernel
    fused_kernel<<<1944, 192, 0, stream>>>(x, W2, TAB, g, w_i, bias, outp);
}

// Round 9
// 133.785 us; speedup vs baseline: 2.5441x; 2.4826x over previous
//
#include <hip/hip_runtime.h>

// ---------------------------------------------------------------------------
// Factorized algorithm (verified rounds 2-11). Shells = ascending r2 rank:
//   r2 in {0,1,2,3,4,5,6,8,9,12} -> shell 0..9
// y[l][r][d][z] = sum_{taps t in shell r} sph_l[t] * x[d, xo+i, yo+j, z+kk]
// conv_r[s,e,z] = sum_{r,d} wfull[wig_w[s], r, e, d] * y[wig_b[s]][r][d][z]
// s=0:(w,b)=(0,0); s=1..9: w=1+(s-1)/3, b=1+(s-1)%3
// Round 17 (153us, base): 4 super-phases x 4 d, 4z/thread stage-1, packed
//   symmetric CT in LDS, Y2 k-parity XOR banking, XT pitch-20. VGPR 128.
// Rounds 18/19/20 all regressed via VGPR-allocator blowups (192/144/224) --
//   reverted. Structure below is r17 EXACTLY except stage-2 arithmetic.
// Round 21: packed-FP32 stage-2. acc -> f32x2[10][2] (z in vector lanes);
//   y loaded as {yb[l], yb[l+96]} pairs -> ds_read2_b32 (offsets 0/96 dw,
//   zero movs, 8-lane broadcast per addr -> conflict-free); 40 scalar FMA/k
//   -> 20 v_pk_fma_f32 (scalar w broadcasts; ffp-contract=fast packs).
//   Per-k instr 44 -> 26; ~2900 instrs/thread off the critical path.
//   NO launch_bounds min-waves (r14); stages in separate intervals (r16).
// ---------------------------------------------------------------------------

typedef __attribute__((ext_vector_type(2))) float f32x2;

// prep: W2[p8][k20][e16][w4] (k=2r+di, d=2p+di) + CT3[l][25][4] packed
__global__ void prep_kernel(const float* __restrict__ weight,     // (4,9,16,16)
                            const float* __restrict__ zw,         // (16,16)
                            const float* __restrict__ bf,         // (4,10,125)
                            float* __restrict__ W2,               // 10240 f32
                            float* __restrict__ TAB)              // 400 f32
{
    int t = blockIdx.x * 256 + threadIdx.x;
    if (t < 10240) {
        int w = t & 3;
        int e = (t >> 2) & 15;
        int k = (t >> 6) % 20;
        int p = t / 1280;
        int r = k >> 1, di = k & 1, d = 2 * p + di;
        float v;
        if (r == 0) v = (w == 0) ? zw[e * 16 + d] : 0.f;
        else        v = weight[((w * 9 + (r - 1)) * 16 + e) * 16 + d];
        W2[t] = v;
    } else if (t < 10240 + 400) {
        int q = t - 10240;           // [l4][25][4] = {c(kk=0),c(1),c(2),sign}
        int l = q / 100;
        int rem = q % 100;
        int slice = rem / 4, qq = rem & 3;
        float s;
        if (qq == 3) {
            s = (l == 2) ? -1.f : 1.f;   // c(3)=s*c(1), c(4)=s*c(0)
        } else {
            s = 0.f;
            int tap = slice * 5 + qq;
            for (int r = 0; r < 10; ++r) s += bf[(l * 10 + r) * 125 + tap];
        }
        TAB[q] = s;                  // sph_l[tap] (masks partition the cube)
    }
}

__global__ __launch_bounds__(192) void fused_kernel(
    const float* __restrict__ x,    // (2,16,40,40,40)
    const float* __restrict__ W2,   // [p][k20][e16][w4]
    const float* __restrict__ TAB,  // CT3 [l][25][4]
    const float* __restrict__ g,    // (27,10)
    const float* __restrict__ w_i,  // (3,)
    const float* __restrict__ bias, // (16,)
    float* __restrict__ out)        // (2,16,36,36,36)
{
    __shared__ float Y2[7680];      // [k40][bank-permuted (yo,z,l)] see below
    __shared__ float CT[400];       // [l4][25][4] packed symmetric coeffs
    __shared__ float XT[3232];      // [sd4 pitch 808][i5][row8][20]

    const int tid = threadIdx.x;

    // XCD-chunked swizzle: 1944 blocks = 8 XCDs x 243 contiguous wgids
    const int bid  = blockIdx.x;
    const int wgid = (bid & 7) * 243 + (bid >> 3);
    const int xo  = wgid % 36;
    const int yoq = (wgid / 36) % 9;
    const int zs  = (wgid / 324) % 3;   // z base = 12*zs
    const int bb  = wgid / 972;

    // stage-1 decode: zt = wave (3), lane -> (sd4, l4, yo4); 4 z per thread
    const int s_zt = tid >> 6;          // 0..2, z = 4*s_zt + zz
    const int lane = tid & 63;
    const int s_sd = lane >> 4;         // 0..3  (d = 4*pp + s_sd)
    const int s_l  = (lane >> 2) & 3;
    const int s_yo = lane & 3;
    // stage-2 decode (e8, yo4, zt6): e = 2*c_e+{0,1}, z = 2*c_zt+{0,1}
    const int c_e  = tid & 7;
    const int c_yo = (tid >> 3) & 3;
    const int c_zt = tid / 32;

    for (int idx = tid; idx < 400; idx += 192) CT[idx] = TAB[idx];

    constexpr int RANKT[13] = {0, 1, 2, 3, 4, 5, 6, 0, 7, 8, 0, 0, 9};

    f32x2 acc[10][2];   // [s][e-sub], vector lanes = (z0, z1) = 40 VGPRs
    #pragma unroll
    for (int s = 0; s < 10; ++s)
        #pragma unroll
        for (int ee = 0; ee < 2; ++ee) acc[s][ee] = (f32x2){0.f, 0.f};

    // Y2 word(k', yo, z, l) = k'*192 + (z&1)*96 + (z>>2)*32
    //                         + (((z>>1)&1) ^ (k'&1))*16 + yo*4 + l
    // stage-1 writes: 2-way (free); stage-2 reads conflict-free.
    const int s1b  = s_sd & 1;
    const int kb   = (s_sd >> 1) * 20 + s1b;     // k' = kb + 2r
    const int wb0  = s_zt * 32 + s_yo * 4 + s_l;
    const int offa = s1b ? 16 : 0;               // zz=0,1 slot
    const int offb = 16 - offa;                  // zz=2,3 slot
    const int ybA  = (c_zt >> 1) * 32 + (c_zt & 1) * 16 + c_yo * 4;  // k' even
    const int ybB  = ybA ^ 16;                                        // k' odd

    // ---- XT staging geometry: 640 float4 per super-phase, 4 slots ----
    // decode j in LOW 3 bits -> conflict-free b128 LDS writes
    int xtoff[4], goff[4];
    #pragma unroll
    for (int q = 0; q < 4; ++q) {
        const int idx = tid + 192 * q;
        const int j  = idx & 7;
        const int zq = (idx >> 3) & 3;
        const int ii = (idx >> 5) % 5;
        const int sd = idx / 160;               // 0..3 (idx<640)
        xtoff[q] = sd * 808 + (ii * 8 + j) * 20 + 4 * zq;
        goff[q]  = sd * 64000 + ((xo + ii) * 40 + yoq * 4 + j) * 40
                   + zs * 12 + 4 * zq;
    }
    const bool has3 = tid < 64;                 // slot 3 active iff idx<640
    const float* xbase = x + bb * 1024000;

    // prologue: XT(0) direct; prefetch super-phase 1
    {
        float4 v0 = *(const float4*)(xbase + goff[0]);
        float4 v1 = *(const float4*)(xbase + goff[1]);
        float4 v2 = *(const float4*)(xbase + goff[2]);
        float4 v3 = has3 ? *(const float4*)(xbase + goff[3])
                         : make_float4(0.f, 0.f, 0.f, 0.f);
        *(float4*)(XT + xtoff[0]) = v0;
        *(float4*)(XT + xtoff[1]) = v1;
        *(float4*)(XT + xtoff[2]) = v2;
        if (has3) *(float4*)(XT + xtoff[3]) = v3;
    }
    float4 pre[4];
    {
        const float* b1 = xbase + 256000;
        pre[0] = *(const float4*)(b1 + goff[0]);
        pre[1] = *(const float4*)(b1 + goff[1]);
        pre[2] = *(const float4*)(b1 + goff[2]);
        pre[3] = has3 ? *(const float4*)(b1 + goff[3])
                      : make_float4(0.f, 0.f, 0.f, 0.f);
    }

    for (int pp = 0; pp < 4; ++pp) {
        __syncthreads();   // A: XT(pp) ready; stage-2(pp-1) done (Y2 free)
        // ---- stage 1: 4 z, d = 4*pp + s_sd, l = s_l (from XT + CT) ----
        {
            float yreg[10][4];
            #pragma unroll
            for (int r = 0; r < 10; ++r) {
                yreg[r][0] = 0.f; yreg[r][1] = 0.f;
                yreg[r][2] = 0.f; yreg[r][3] = 0.f;
            }
            const float* xt  = XT + s_sd * 808 + 4 * s_zt;
            const float* ctp = CT + s_l * 100;
            #pragma unroll
            for (int i = 0; i < 5; ++i) {
                #pragma unroll
                for (int j = 0; j < 5; ++j) {
                    const float* rp = xt + (i * 8 + s_yo + j) * 20;
                    const float4 xa = *(const float4*)rp;
                    const float4 xb = *(const float4*)(rp + 4);
                    const float xv[8] = {xa.x, xa.y, xa.z, xa.w,
                                         xb.x, xb.y, xb.z, xb.w};
                    const float4 cc = *(const float4*)(ctp + (i * 5 + j) * 4);
                    const int dij = (i - 2) * (i - 2) + (j - 2) * (j - 2);
                    const int r04 = RANKT[dij + 4];
                    const int r13 = RANKT[dij + 1];
                    const int r2c = RANKT[dij];
                    #pragma unroll
                    for (int zz = 0; zz < 4; ++zz) {
                        const float t04 = fmaf(cc.w, xv[zz + 4], xv[zz]);
                        const float t13 = fmaf(cc.w, xv[zz + 3], xv[zz + 1]);
                        yreg[r04][zz] = fmaf(cc.x, t04, yreg[r04][zz]);
                        yreg[r13][zz] = fmaf(cc.y, t13, yreg[r13][zz]);
                        yreg[r2c][zz] = fmaf(cc.z, xv[zz + 2], yreg[r2c][zz]);
                    }
                }
            }
            #pragma unroll
            for (int r = 0; r < 10; ++r) {
                const int w0 = (kb + 2 * r) * 192 + wb0;
                Y2[w0 + offa]      = yreg[r][0];   // pairs fuse to ds_write2
                Y2[w0 + offa + 96] = yreg[r][1];
                Y2[w0 + offb]      = yreg[r][2];
                Y2[w0 + offb + 96] = yreg[r][3];
            }
        }
        __syncthreads();   // B: Y2 ready; XT(pp) readers done
        // ---- write XT(pp+1) from prefetch; issue loads for pp+2 ----
        if (pp < 3) {
            *(float4*)(XT + xtoff[0]) = pre[0];
            *(float4*)(XT + xtoff[1]) = pre[1];
            *(float4*)(XT + xtoff[2]) = pre[2];
            if (has3) *(float4*)(XT + xtoff[3]) = pre[3];
            if (pp < 2) {
                const float* bn = xbase + (pp + 2) * 256000;
                pre[0] = *(const float4*)(bn + goff[0]);
                pre[1] = *(const float4*)(bn + goff[1]);
                pre[2] = *(const float4*)(bn + goff[2]);
                if (has3) pre[3] = *(const float4*)(bn + goff[3]);
            }
        }
        // ---- stage 2 (E=2): packed over z; y as ds_read2_b32 pairs ----
        {
            const float* W2p = W2 + pp * 2560 + c_e * 8;
            #pragma unroll
            for (int k = 0; k < 40; ++k) {
                const float4 wv0 = *(const float4*)(W2p + k * 64);
                const float4 wv1 = *(const float4*)(W2p + k * 64 + 4);
                const float* yb = Y2 + k * 192 + ((k & 1) ? ybB : ybA);
                // z-pairs land in aligned VGPR pairs (ds_read2_b32, off 0/96)
                const f32x2 y0 = {yb[0], yb[96]};
                const f32x2 y1 = {yb[1], yb[97]};
                const f32x2 y2 = {yb[2], yb[98]};
                const f32x2 y3 = {yb[3], yb[99]};
                // b = 0 pairs only with w = 0 -> s = 0
                acc[0][0] += wv0.x * y0;       // v_pk_fma_f32
                acc[0][1] += wv1.x * y0;
                // b = 1..3 (y1..y3) x w = 1..3 -> s = 1 + (w-1)*3 + (b-1)
                acc[1][0] += wv0.y * y1;  acc[1][1] += wv1.y * y1;
                acc[2][0] += wv0.y * y2;  acc[2][1] += wv1.y * y2;
                acc[3][0] += wv0.y * y3;  acc[3][1] += wv1.y * y3;
                acc[4][0] += wv0.z * y1;  acc[4][1] += wv1.z * y1;
                acc[5][0] += wv0.z * y2;  acc[5][1] += wv1.z * y2;
                acc[6][0] += wv0.z * y3;  acc[6][1] += wv1.z * y3;
                acc[7][0] += wv0.w * y1;  acc[7][1] += wv1.w * y1;
                acc[8][0] += wv0.w * y2;  acc[8][1] += wv1.w * y2;
                acc[9][0] += wv0.w * y3;  acc[9][1] += wv1.w * y3;
            }
        }
    }

    // ---- epilogue: SO(3)-grid + self-normalized pooling (2 e, z-pair) ----
    const float wi0 = w_i[0], wi1 = w_i[1], wi2 = w_i[2];
    f32x2 num[2], den[2];
    #pragma unroll
    for (int ee = 0; ee < 2; ++ee) {
        num[ee] = (f32x2){0.f, 0.f};
        den[ee] = (f32x2){0.f, 0.f};
    }
    #pragma unroll
    for (int q = 0; q < 27; ++q) {
        const float wl = ((q / 3) % 3 == 0) ? wi0 : (((q / 3) % 3 == 1) ? wi1 : wi2);
        float gv[10];
        #pragma unroll
        for (int s = 0; s < 10; ++s) gv[s] = g[q * 10 + s];  // uniform -> s_load
        #pragma unroll
        for (int ee = 0; ee < 2; ++ee) {
            f32x2 v = (f32x2){0.f, 0.f};
            #pragma unroll
            for (int s = 0; s < 10; ++s) v += acc[s][ee] * gv[s];
            v.x = fmaxf(v.x, 0.f);
            v.y = fmaxf(v.y, 0.f);
            den[ee] += v * wl;
            num[ee] += v * v * wl;
        }
    }
    #pragma unroll
    for (int ee = 0; ee < 2; ++ee) {
        const int e = 2 * c_e + ee;
        const float bz = bias[e];
        float* op = out + (((bb * 16 + e) * 36 + xo) * 36 + (yoq * 4 + c_yo)) * 36
                        + zs * 12 + 2 * c_zt;
        *(float2*)op = make_float2(num[ee].x / (den[ee].x + 1e-16f) + bz,
                                   num[ee].y / (den[ee].y + 1e-16f) + bz);
    }
}

extern "C" void kernel_launch(void* const* d_in, const int* in_sizes, int n_in,
                              void* d_out, int out_size, void* d_ws, size_t ws_size,
                              hipStream_t stream) {
    const float* x          = (const float*)d_in[0];
    const float* weight     = (const float*)d_in[1];
    const float* zeroweight = (const float*)d_in[2];
    const float* bias       = (const float*)d_in[3];
    const float* g          = (const float*)d_in[4];
    const float* w_i        = (const float*)d_in[5];
    const float* bf         = (const float*)d_in[6];
    float* outp = (float*)d_out;

    float* W2  = (float*)d_ws;            // 10240 f32
    float* TAB = (float*)d_ws + 10240;    // 400 f32 (packed CT3 layout)

    prep_kernel<<<42, 256, 0, stream>>>(weight, zeroweight, bf, W2, TAB);
    // 1944 blocks = 36 xo * 9 yoq * 3 zs * 2 b, XCD-swizzled in-kernel
    fused_kernel<<<1944, 192, 0, stream>>>(x, W2, TAB, g, w_i, bias, outp);
}